// Round 9
// baseline (638.982 us; speedup 1.0000x reference)
//
#include <hip/hip_runtime.h>
#include <hip/hip_bf16.h>
#include <stdint.h>

#define B_ 4
#define S_ 128
#define CH 512

typedef __attribute__((ext_vector_type(8))) __bf16 bf16x8;
typedef __attribute__((ext_vector_type(4))) float  f32x4;
typedef __attribute__((ext_vector_type(16))) float f32x16;

__device__ __forceinline__ unsigned short f2b(float f) {
    union { float f; unsigned u; } v; v.f = f;
    unsigned r = v.u + 0x7FFFu + ((v.u >> 16) & 1u);
    return (unsigned short)(r >> 16);
}

#define GLD_LDS16(gp, lp) \
    __builtin_amdgcn_global_load_lds((const __attribute__((address_space(1))) void*)(gp), \
                                     (__attribute__((address_space(3))) void*)(lp), 16, 0, 0)

// ---------------- weights f32 -> bf16 ----------------
__global__ void cvt_w(const float* __restrict__ wq, const float* __restrict__ wp,
                      unsigned short* __restrict__ wqb, unsigned short* __restrict__ wpb) {
    int idx = (blockIdx.x * 256 + threadIdx.x) * 4;
    const float* s; unsigned short* d; int off;
    if (idx < 1536 * 512) { s = wq; d = wqb; off = idx; }
    else                  { s = wp; d = wpb; off = idx - 1536 * 512; }
    float4 v = *(const float4*)(s + off);
    ushort4 o; o.x = f2b(v.x); o.y = f2b(v.y); o.z = f2b(v.z); o.w = f2b(v.w);
    *(ushort4*)(d + off) = o;
}

// ------- x[b][c][h][w] f32 -> Xb[(b*128+w)*128+h][c] bf16 -------
__global__ __launch_bounds__(256) void k0_tr(const float* __restrict__ x,
                                             unsigned short* __restrict__ xb) {
    __shared__ unsigned short t[64][72];
    int bid = blockIdx.x;
    int ct = bid & 7, wt = (bid >> 3) & 1, h = (bid >> 4) & 127, b = bid >> 11;
    int tid = threadIdx.x;
    int c0 = ct * 64, w0 = wt * 64;
    const float* xp = x + ((size_t)b * CH * S_ + h) * S_;
    int wl = (tid & 15) * 4;
#pragma unroll
    for (int it = 0; it < 4; ++it) {
        int c = it * 16 + (tid >> 4);
        float4 v = *(const float4*)(xp + (size_t)(c0 + c) * (S_ * S_) + w0 + wl);
        t[wl + 0][c] = f2b(v.x);
        t[wl + 1][c] = f2b(v.y);
        t[wl + 2][c] = f2b(v.z);
        t[wl + 3][c] = f2b(v.w);
    }
    __syncthreads();
#pragma unroll
    for (int it = 0; it < 2; ++it) {
        int w = it * 32 + (tid >> 3);
        int ce = (tid & 7) * 8;
        int4 v = *(const int4*)&t[w][ce];
        size_t p = (size_t)((b * 128 + w0 + w) * 128 + h);
        *(int4*)(xb + p * 512 + c0 + ce) = v;
    }
}

// ===== 256x256 GEMM (32x32x16), BK=32, read-once-to-regs, 3-buf depth-2 =====
// 8 waves (2M x 4N), wave tile 128x64. Per K-tile (BK=32) each wave reads ALL
// its operands ONCE: A 8 b128 + B 4 b128 (24 KB per K64 = the (Mw+Nw)*K
// minimum; r7/r8 read 32 KB via B double-reads). 16 MFMA 32x32x16 per tile.
// LDS: 3 buffers x (A 16KB + B 16KB) = 96 KB. Pipeline: at tile j stage tile
// j+2 (4 GLD/wave); end of tile j: vmcnt(4) retires (FIFO) everything older
// than tile j+2's 4 loads == tile j+1 fully landed; barrier publishes.
// Overwrite safety: STAGE(j+2) targets buf[(j+2)%3]=buf[(j-1)%3], whose last
// reads completed before the end-of-(j-1) barrier, which precedes the issue.
// Chunk swizzle (16B granules): stored_chunk = data_chunk ^ (row&3); staging
// keeps LDS linear (dest = base + lane*16B -> row=l>>2, chunk=l&3) and
// inverse-permutes the per-lane GLOBAL source chunk = (l&3)^((l>>2)&3).
// Fragment reads then hit 2-way banks at worst (free, m136).
template<int EPI>
__global__ __launch_bounds__(512, 2) void gemm8(
    const unsigned short* __restrict__ A,
    const unsigned short* __restrict__ Bm,
    unsigned short* __restrict__ outb,
    const float* __restrict__ xres,
    float* __restrict__ outf,
    int Mtiles)
{
    __shared__ unsigned short lds[49152];   // 3 x (A 8192 | B 8192) ushorts
    const int NT = 16;                      // 512 / BK(32)
    int nwg = gridDim.x;
    int wg = (blockIdx.x & 7) * (nwg >> 3) + (blockIdx.x >> 3);  // T1 XCD swizzle
    int mb = wg % Mtiles, nb = wg / Mtiles;
    int m0 = mb * 256, n0 = nb * 256;
    int tid = threadIdx.x, lane = tid & 63, wid = tid >> 6;
    int wm = wid >> 2, wn = wid & 3;

    f32x16 acc[4][2] = {};   // [mq][nq]

    // fragment-read constants: row = <block> + l31, want chunk ks*2+(l>>5),
    // stored chunk = want ^ (row&3) = want ^ (lane&3)
    int l31  = lane & 31;
    int ck[2];
#pragma unroll
    for (int ks = 0; ks < 2; ++ks)
        ck[ks] = (((ks * 2 + (lane >> 5)) ^ (lane & 3)) << 3);
    int arow = (wm * 128 + l31) * 32;      // + mq*1024
    int brow = (wn * 64 + l31) * 32;       // + nq*1024 (B base +8192)

    // staging: per-wave linear LDS dest; per-lane global src chunk-permuted
    int dchunk = (lane & 3) ^ ((lane >> 2) & 3);
    const unsigned short* Asrc = A  + (size_t)(m0 + 16 * wid + (lane >> 2)) * 512 + dchunk * 8;
    const unsigned short* Bsrc = Bm + (size_t)(n0 + 16 * wid + (lane >> 2)) * 512 + dchunk * 8;

#define STAGE(buf, kt) do {                                                    \
        unsigned short* la_ = &lds[(buf) * 16384 + 16 * wid * 32];             \
        unsigned short* lb_ = la_ + 8192;                                      \
        GLD_LDS16(Asrc + (kt) * 32,             la_);                          \
        GLD_LDS16(Asrc + 128 * 512 + (kt) * 32, la_ + 4096);                   \
        GLD_LDS16(Bsrc + (kt) * 32,             lb_);                          \
        GLD_LDS16(Bsrc + 128 * 512 + (kt) * 32, lb_ + 4096);                   \
    } while (0)

    // prologue: tiles 0 and 1
    STAGE(0, 0); STAGE(1, 1);
    asm volatile("s_waitcnt vmcnt(4)" ::: "memory");   // tile0's 4 loads done
    __builtin_amdgcn_s_barrier();

    for (int j = 0; j < NT; ++j) {
        const int buf = j % 3;
        if (j + 2 < NT) STAGE((j + 2) % 3, j + 2);
        bf16x8 af[4][2], bq[2][2];
        {
            int ab = buf * 16384 + arow;
#pragma unroll
            for (int mq = 0; mq < 4; ++mq)
#pragma unroll
                for (int ks = 0; ks < 2; ++ks)
                    af[mq][ks] = *(const bf16x8*)&lds[ab + mq * 1024 + ck[ks]];
            int bb = buf * 16384 + 8192 + brow;
#pragma unroll
            for (int nq = 0; nq < 2; ++nq)
#pragma unroll
                for (int ks = 0; ks < 2; ++ks)
                    bq[nq][ks] = *(const bf16x8*)&lds[bb + nq * 1024 + ck[ks]];
        }
        __builtin_amdgcn_s_setprio(1);
#pragma unroll
        for (int ks = 0; ks < 2; ++ks)
#pragma unroll
            for (int mq = 0; mq < 4; ++mq)
#pragma unroll
                for (int nq = 0; nq < 2; ++nq)
                    acc[mq][nq] = __builtin_amdgcn_mfma_f32_32x32x16_bf16(
                        af[mq][ks], bq[nq][ks], acc[mq][nq], 0, 0, 0);
        __builtin_amdgcn_s_setprio(0);
        if (j + 2 < NT)      asm volatile("s_waitcnt vmcnt(4)" ::: "memory");
        else if (j == NT - 2) asm volatile("s_waitcnt vmcnt(0)" ::: "memory");
        if (j < NT - 1) __builtin_amdgcn_s_barrier();
    }
#undef STAGE

#pragma unroll
    for (int mi2 = 0; mi2 < 4; ++mi2) {
#pragma unroll
        for (int qd = 0; qd < 4; ++qd) {
            int row0 = m0 + wm * 128 + mi2 * 32 + qd * 8 + ((lane >> 5) << 2);
#pragma unroll
            for (int nq = 0; nq < 2; ++nq) {
                int col = n0 + wn * 64 + nq * 32 + (lane & 31);
                int i = col & 127, sq = (col >> 7) & 127, bb = col >> 14;
                float a4[4];
#pragma unroll
                for (int r = 0; r < 4; ++r) a4[r] = acc[mi2][nq][qd * 4 + r];
                if (EPI == 0) {
                    int g = row0 >> 6, d0 = row0 & 63;
                    if (g < 16) {
                        size_t base = ((size_t)(g * 4 + bb) * 16384 + (size_t)sq * 128 + i) * 64 + d0;
                        ushort4 o;
                        o.x = f2b(a4[0]); o.y = f2b(a4[1]); o.z = f2b(a4[2]); o.w = f2b(a4[3]);
                        *(ushort4*)(outb + base) = o;
                    } else {
                        size_t base = ((size_t)(g * 4 + bb) * 8192 + (size_t)sq * 64 + d0) * 128 + i;
                        outb[base]       = f2b(a4[0]);
                        outb[base + 128] = f2b(a4[1]);
                        outb[base + 256] = f2b(a4[2]);
                        outb[base + 384] = f2b(a4[3]);
                    }
                } else if (EPI == 1) {
                    size_t p2 = ((size_t)bb * 128 + i) * 128 + sq;
                    ushort4 o;
                    o.x = f2b(a4[0]); o.y = f2b(a4[1]); o.z = f2b(a4[2]); o.w = f2b(a4[3]);
                    *(ushort4*)(outb + p2 * 512 + row0) = o;
                } else {
                    size_t base = (((size_t)bb * 512 + row0) * 128 + sq) * 128 + i;
#pragma unroll
                    for (int r = 0; r < 4; ++r) {
                        size_t a_ = base + (size_t)r * 16384;
                        outf[a_] = xres[a_] + a4[r];
                    }
                }
            }
        }
    }
}

// ---------------- attention: one block per (b, seq, head) ----------------
__global__ __launch_bounds__(256) void attn_k(const unsigned short* __restrict__ qkv,
                                              unsigned short* __restrict__ o2) {
    __shared__ unsigned short Qs[128 * 80];
    __shared__ unsigned short Ks[128 * 80];
    __shared__ unsigned short Vt[64 * 144];
    int bid = blockIdx.x;
    int t = bid & 7, sq = (bid >> 3) & 127, b = bid >> 10;
    int tid = threadIdx.x, lane = tid & 63, wv = tid >> 6;
    const unsigned short* qg = qkv + ((size_t)(t * 4 + b) * 16384 + (size_t)sq * 128) * 64;
    const unsigned short* kg = qkv + ((size_t)((8 + t) * 4 + b) * 16384 + (size_t)sq * 128) * 64;
    const unsigned short* vg = qkv + ((size_t)((16 + t) * 4 + b) * 8192 + (size_t)sq * 64) * 128;
    {
        int r = tid >> 3, d0 = (tid & 7) * 8;
#pragma unroll
        for (int it = 0; it < 4; ++it) {
            *(int4*)(Qs + (it * 32 + r) * 80 + d0) = *(const int4*)(qg + (it * 32 + r) * 64 + d0);
            *(int4*)(Ks + (it * 32 + r) * 80 + d0) = *(const int4*)(kg + (it * 32 + r) * 64 + d0);
        }
        int r2 = tid >> 4, i0 = (tid & 15) * 8;
#pragma unroll
        for (int it = 0; it < 4; ++it)
            *(int4*)(Vt + (it * 16 + r2) * 144 + i0) = *(const int4*)(vg + (it * 16 + r2) * 128 + i0);
    }
    __syncthreads();

    f32x4 st[8][2] = {};
#pragma unroll
    for (int kk = 0; kk < 2; ++kk) {
        int ko = kk * 32 + (lane >> 4) * 8;
        bf16x8 bq[2];
#pragma unroll
        for (int nt = 0; nt < 2; ++nt)
            bq[nt] = *(const bf16x8*)(Qs + (wv * 32 + nt * 16 + (lane & 15)) * 80 + ko);
#pragma unroll
        for (int mt = 0; mt < 8; ++mt) {
            bf16x8 ak = *(const bf16x8*)(Ks + (mt * 16 + (lane & 15)) * 80 + ko);
#pragma unroll
            for (int nt = 0; nt < 2; ++nt)
                st[mt][nt] = __builtin_amdgcn_mfma_f32_16x16x32_bf16(ak, bq[nt], st[mt][nt], 0, 0, 0);
        }
    }

    const float sc = 0.125f * 1.44269504088896f;
    float mx[2], rinv[2];
    unsigned ppk[8][2][2];
#pragma unroll
    for (int nt = 0; nt < 2; ++nt) {
        float m = -3.0e38f;
#pragma unroll
        for (int mt = 0; mt < 8; ++mt)
#pragma unroll
            for (int r = 0; r < 4; ++r)
                m = fmaxf(m, st[mt][nt][r]);
        m = fmaxf(m, __shfl_xor(m, 16));
        m = fmaxf(m, __shfl_xor(m, 32));
        mx[nt] = m * sc;
    }
#pragma unroll
    for (int nt = 0; nt < 2; ++nt) {
        float s = 0.f;
#pragma unroll
        for (int mt = 0; mt < 8; ++mt) {
            float p0 = exp2f(st[mt][nt][0] * sc - mx[nt]);
            float p1 = exp2f(st[mt][nt][1] * sc - mx[nt]);
            float p2 = exp2f(st[mt][nt][2] * sc - mx[nt]);
            float p3 = exp2f(st[mt][nt][3] * sc - mx[nt]);
            s += (p0 + p1) + (p2 + p3);
            ppk[mt][nt][0] = (unsigned)f2b(p0) | ((unsigned)f2b(p1) << 16);
            ppk[mt][nt][1] = (unsigned)f2b(p2) | ((unsigned)f2b(p3) << 16);
        }
        s += __shfl_xor(s, 16);
        s += __shfl_xor(s, 32);
        rinv[nt] = 1.0f / s;
    }

    f32x4 ov[4][2] = {};
    int g = lane >> 4;
    int ls0 = (lane & 15) | ((g & 1) << 5);
    int ls1 = ls0 | 16;
    int hi = g >> 1;
#pragma unroll
    for (int kt = 0; kt < 4; ++kt) {
        bf16x8 bp[2];
#pragma unroll
        for (int nt = 0; nt < 2; ++nt) {
            unsigned a0 = (unsigned)__shfl((int)ppk[2 * kt    ][nt][0], ls0);
            unsigned b0 = (unsigned)__shfl((int)ppk[2 * kt + 1][nt][0], ls0);
            unsigned a1 = (unsigned)__shfl((int)ppk[2 * kt    ][nt][1], ls0);
            unsigned b1 = (unsigned)__shfl((int)ppk[2 * kt + 1][nt][1], ls0);
            unsigned a2 = (unsigned)__shfl((int)ppk[2 * kt    ][nt][0], ls1);
            unsigned b2 = (unsigned)__shfl((int)ppk[2 * kt + 1][nt][0], ls1);
            unsigned a3 = (unsigned)__shfl((int)ppk[2 * kt    ][nt][1], ls1);
            unsigned b3 = (unsigned)__shfl((int)ppk[2 * kt + 1][nt][1], ls1);
            union { unsigned u[4]; bf16x8 v; } pk;
            pk.u[0] = hi ? b0 : a0;
            pk.u[1] = hi ? b1 : a1;
            pk.u[2] = hi ? b2 : a2;
            pk.u[3] = hi ? b3 : a3;
            bp[nt] = pk.v;
        }
#pragma unroll
        for (int dt = 0; dt < 4; ++dt) {
            bf16x8 av = *(const bf16x8*)(Vt + (dt * 16 + (lane & 15)) * 144 + kt * 32 + (lane >> 4) * 8);
#pragma unroll
            for (int nt = 0; nt < 2; ++nt)
                ov[dt][nt] = __builtin_amdgcn_mfma_f32_16x16x32_bf16(av, bp[nt], ov[dt][nt], 0, 0, 0);
        }
    }

#pragma unroll
    for (int dt = 0; dt < 4; ++dt) {
        int d0 = dt * 16 + (lane >> 4) * 4;
#pragma unroll
        for (int nt = 0; nt < 2; ++nt) {
            int i = wv * 32 + nt * 16 + (lane & 15);
            size_t p = ((size_t)(b * 128 + sq)) * 128 + i;
            ushort4 o;
            o.x = f2b(ov[dt][nt][0] * rinv[nt]);
            o.y = f2b(ov[dt][nt][1] * rinv[nt]);
            o.z = f2b(ov[dt][nt][2] * rinv[nt]);
            o.w = f2b(ov[dt][nt][3] * rinv[nt]);
            *(ushort4*)(o2 + p * 512 + t * 64 + d0) = o;
        }
    }
}

extern "C" void kernel_launch(void* const* d_in, const int* in_sizes, int n_in,
                              void* d_out, int out_size, void* d_ws, size_t ws_size,
                              hipStream_t stream) {
    const float* x  = (const float*)d_in[0];
    const float* wq = (const float*)d_in[1];
    const float* wp = (const float*)d_in[2];
    float* out = (float*)d_out;
    char* ws = (char*)d_ws;
    unsigned short* wqb = (unsigned short*)(ws);
    unsigned short* wpb = (unsigned short*)(ws + ((size_t)2 << 20));
    unsigned short* xb  = (unsigned short*)(ws + ((size_t)4 << 20));
    unsigned short* o2  = (unsigned short*)(ws + ((size_t)68 << 20));
    unsigned short* qkv = (unsigned short*)(ws + ((size_t)132 << 20));

    cvt_w<<<1024, 256, 0, stream>>>(wq, wp, wqb, wpb);
    k0_tr<<<8192, 256, 0, stream>>>(x, xb);
    // pass 1 (axis = h)
    gemm8<0><<<6 * 256, 512, 0, stream>>>(wqb, xb, qkv, nullptr, nullptr, 6);
    attn_k<<<4096, 256, 0, stream>>>(qkv, o2);
    gemm8<1><<<2 * 256, 512, 0, stream>>>(wpb, o2, xb, nullptr, nullptr, 2);
    // pass 2 (axis = w)
    gemm8<0><<<6 * 256, 512, 0, stream>>>(wqb, xb, qkv, nullptr, nullptr, 6);
    attn_k<<<4096, 256, 0, stream>>>(qkv, o2);
    gemm8<2><<<2 * 256, 512, 0, stream>>>(wpb, o2, nullptr, x, out, 2);
}

// Round 10
// 626.357 us; speedup vs baseline: 1.0202x; 1.0202x over previous
//
#include <hip/hip_runtime.h>
#include <hip/hip_bf16.h>
#include <stdint.h>

#define B_ 4
#define S_ 128
#define CH 512

typedef __attribute__((ext_vector_type(8))) __bf16 bf16x8;
typedef __attribute__((ext_vector_type(4))) float  f32x4;
typedef __attribute__((ext_vector_type(16))) float f32x16;

__device__ __forceinline__ unsigned short f2b(float f) {
    union { float f; unsigned u; } v; v.f = f;
    unsigned r = v.u + 0x7FFFu + ((v.u >> 16) & 1u);
    return (unsigned short)(r >> 16);
}

#define GLD_LDS16(gp, lp) \
    __builtin_amdgcn_global_load_lds((const __attribute__((address_space(1))) void*)(gp), \
                                     (__attribute__((address_space(3))) void*)(lp), 16, 0, 0)

// ---------------- weights f32 -> bf16 ----------------
__global__ void cvt_w(const float* __restrict__ wq, const float* __restrict__ wp,
                      unsigned short* __restrict__ wqb, unsigned short* __restrict__ wpb) {
    int idx = (blockIdx.x * 256 + threadIdx.x) * 4;
    const float* s; unsigned short* d; int off;
    if (idx < 1536 * 512) { s = wq; d = wqb; off = idx; }
    else                  { s = wp; d = wpb; off = idx - 1536 * 512; }
    float4 v = *(const float4*)(s + off);
    ushort4 o; o.x = f2b(v.x); o.y = f2b(v.y); o.z = f2b(v.z); o.w = f2b(v.w);
    *(ushort4*)(d + off) = o;
}

// ------- x[b][c][h][w] f32 -> Xb[(b*128+w)*128+h][c] bf16 -------
__global__ __launch_bounds__(256) void k0_tr(const float* __restrict__ x,
                                             unsigned short* __restrict__ xb) {
    __shared__ unsigned short t[64][72];
    int bid = blockIdx.x;
    int ct = bid & 7, wt = (bid >> 3) & 1, h = (bid >> 4) & 127, b = bid >> 11;
    int tid = threadIdx.x;
    int c0 = ct * 64, w0 = wt * 64;
    const float* xp = x + ((size_t)b * CH * S_ + h) * S_;
    int wl = (tid & 15) * 4;
#pragma unroll
    for (int it = 0; it < 4; ++it) {
        int c = it * 16 + (tid >> 4);
        float4 v = *(const float4*)(xp + (size_t)(c0 + c) * (S_ * S_) + w0 + wl);
        t[wl + 0][c] = f2b(v.x);
        t[wl + 1][c] = f2b(v.y);
        t[wl + 2][c] = f2b(v.z);
        t[wl + 3][c] = f2b(v.w);
    }
    __syncthreads();
#pragma unroll
    for (int it = 0; it < 2; ++it) {
        int w = it * 32 + (tid >> 3);
        int ce = (tid & 7) * 8;
        int4 v = *(const int4*)&t[w][ce];
        size_t p = (size_t)((b * 128 + w0 + w) * 128 + h);
        *(int4*)(xb + p * 512 + c0 + ce) = v;
    }
}

// ===== 128x128 GEMM (32x32x16), 4 waves, BK=32, 3-buf depth-2, 3 blocks/CU ===
// TLP-first structure: 4-wave blocks (wave tile 64x64, acc 4xf32x16 = 64 VGPR),
// LDS 3 x 16KB = 48KB -> 3 blocks/CU, launch_bounds(256,4) caps VGPR at 128 ->
// 12 waves/CU in 3 INDEPENDENT barrier domains (one block's stage/barrier stall
// is covered by the other two; the m97 mechanism).
// Per K32-tile per wave: read-once A 4 b128 + B 4 b128 (LINEAR LDS: 64B-stride
// rows measured at the intrinsic 4.0 cy/read floor across r1-r8; swizzles never
// beat it), 4 GLD stage, 8 MFMA 32x32x16, one counted vmcnt(4), one barrier.
// Pipeline: at tile j stage tile j+2 into buf[(j+2)%3] (= buf[(j-1)%3], whose
// reads finished before the end-of-(j-1) barrier). End of j: vmcnt(4) leaves
// only j+2's 4 GLD outstanding (per-wave FIFO) => tile j+1 fully landed.
template<int EPI>
__global__ __launch_bounds__(256, 4) void gemm8(
    const unsigned short* __restrict__ A,
    const unsigned short* __restrict__ Bm,
    unsigned short* __restrict__ outb,
    const float* __restrict__ xres,
    float* __restrict__ outf,
    int Mtiles)
{
    __shared__ unsigned short lds[24576];   // 3 x (A 4096 | B 4096) ushorts
    const int NT = 16;                      // 512 / BK(32)
    int nwg = gridDim.x;
    int wg = (blockIdx.x & 7) * (nwg >> 3) + (blockIdx.x >> 3);  // T1 XCD swizzle
    int mb = wg % Mtiles, nb = wg / Mtiles;
    int m0 = mb * 128, n0 = nb * 128;
    int tid = threadIdx.x, lane = tid & 63, wid = tid >> 6;
    int wm = wid >> 1, wn = wid & 1;

    f32x16 acc[2][2] = {};   // [mq][nq]

    // fragment-read constants (linear layout): chunk c = 2*ks + (lane>>5)
    int l31  = lane & 31;
    int ck[2];
#pragma unroll
    for (int ks = 0; ks < 2; ++ks)
        ck[ks] = (2 * ks + (lane >> 5)) * 8;
    int arow = (wm * 64 + l31) * 32;       // + mq*32*32
    int brow = 4096 + (wn * 64 + l31) * 32;

    // staging: wave w stages A rows 32w..32w+31 and B rows 32w..32w+31.
    // GLD dest = wave-uniform base + lane*16B -> row = 32w + g*16 + (l>>2),
    // chunk = l&3 (linear). Source matches exactly.
    const unsigned short* Asrc = A  + (size_t)(m0 + 32 * wid + (lane >> 2)) * 512 + (lane & 3) * 8;
    const unsigned short* Bsrc = Bm + (size_t)(n0 + 32 * wid + (lane >> 2)) * 512 + (lane & 3) * 8;

#define STAGE(buf, kt) do {                                                    \
        unsigned short* la_ = &lds[(buf) * 8192 + (32 * wid) * 32];            \
        unsigned short* lb_ = la_ + 4096;                                      \
        GLD_LDS16(Asrc + (kt) * 32,            la_);                           \
        GLD_LDS16(Asrc + 16 * 512 + (kt) * 32, la_ + 512);                     \
        GLD_LDS16(Bsrc + (kt) * 32,            lb_);                           \
        GLD_LDS16(Bsrc + 16 * 512 + (kt) * 32, lb_ + 512);                     \
    } while (0)

    // prologue: tiles 0 and 1
    STAGE(0, 0); STAGE(1, 1);
    asm volatile("s_waitcnt vmcnt(4)" ::: "memory");   // tile0's 4 GLD done
    __builtin_amdgcn_s_barrier();

    for (int j = 0; j < NT; ++j) {
        const int buf = j % 3;
        if (j + 2 < NT) STAGE((j + 2) % 3, j + 2);
        bf16x8 af[2][2], bq[2][2];
        {
            int ab = buf * 8192 + arow;
            int bb = buf * 8192 + brow;
#pragma unroll
            for (int mq = 0; mq < 2; ++mq)
#pragma unroll
                for (int ks = 0; ks < 2; ++ks)
                    af[mq][ks] = *(const bf16x8*)&lds[ab + mq * 1024 + ck[ks]];
#pragma unroll
            for (int nq = 0; nq < 2; ++nq)
#pragma unroll
                for (int ks = 0; ks < 2; ++ks)
                    bq[nq][ks] = *(const bf16x8*)&lds[bb + nq * 1024 + ck[ks]];
        }
        __builtin_amdgcn_s_setprio(1);
#pragma unroll
        for (int ks = 0; ks < 2; ++ks)
#pragma unroll
            for (int mq = 0; mq < 2; ++mq)
#pragma unroll
                for (int nq = 0; nq < 2; ++nq)
                    acc[mq][nq] = __builtin_amdgcn_mfma_f32_32x32x16_bf16(
                        af[mq][ks], bq[nq][ks], acc[mq][nq], 0, 0, 0);
        __builtin_amdgcn_s_setprio(0);
        if (j + 2 < NT)       asm volatile("s_waitcnt vmcnt(4)" ::: "memory");
        else if (j == NT - 2) asm volatile("s_waitcnt vmcnt(0)" ::: "memory");
        if (j < NT - 1) __builtin_amdgcn_s_barrier();
    }
#undef STAGE

#pragma unroll
    for (int mq = 0; mq < 2; ++mq) {
#pragma unroll
        for (int qd = 0; qd < 4; ++qd) {
            int row0 = m0 + wm * 64 + mq * 32 + qd * 8 + ((lane >> 5) << 2);
#pragma unroll
            for (int nq = 0; nq < 2; ++nq) {
                int col = n0 + wn * 64 + nq * 32 + (lane & 31);
                int i = col & 127, sq = (col >> 7) & 127, bb = col >> 14;
                float a4[4];
#pragma unroll
                for (int r = 0; r < 4; ++r) a4[r] = acc[mq][nq][qd * 4 + r];
                if (EPI == 0) {
                    int g = row0 >> 6, d0 = row0 & 63;
                    if (g < 16) {
                        size_t base = ((size_t)(g * 4 + bb) * 16384 + (size_t)sq * 128 + i) * 64 + d0;
                        ushort4 o;
                        o.x = f2b(a4[0]); o.y = f2b(a4[1]); o.z = f2b(a4[2]); o.w = f2b(a4[3]);
                        *(ushort4*)(outb + base) = o;
                    } else {
                        size_t base = ((size_t)(g * 4 + bb) * 8192 + (size_t)sq * 64 + d0) * 128 + i;
                        outb[base]       = f2b(a4[0]);
                        outb[base + 128] = f2b(a4[1]);
                        outb[base + 256] = f2b(a4[2]);
                        outb[base + 384] = f2b(a4[3]);
                    }
                } else if (EPI == 1) {
                    size_t p2 = ((size_t)bb * 128 + i) * 128 + sq;
                    ushort4 o;
                    o.x = f2b(a4[0]); o.y = f2b(a4[1]); o.z = f2b(a4[2]); o.w = f2b(a4[3]);
                    *(ushort4*)(outb + p2 * 512 + row0) = o;
                } else {
                    size_t base = (((size_t)bb * 512 + row0) * 128 + sq) * 128 + i;
#pragma unroll
                    for (int r = 0; r < 4; ++r) {
                        size_t a_ = base + (size_t)r * 16384;
                        outf[a_] = xres[a_] + a4[r];
                    }
                }
            }
        }
    }
}

// ---------------- attention: one block per (b, seq, head) ----------------
__global__ __launch_bounds__(256) void attn_k(const unsigned short* __restrict__ qkv,
                                              unsigned short* __restrict__ o2) {
    __shared__ unsigned short Qs[128 * 80];
    __shared__ unsigned short Ks[128 * 80];
    __shared__ unsigned short Vt[64 * 144];
    int bid = blockIdx.x;
    int t = bid & 7, sq = (bid >> 3) & 127, b = bid >> 10;
    int tid = threadIdx.x, lane = tid & 63, wv = tid >> 6;
    const unsigned short* qg = qkv + ((size_t)(t * 4 + b) * 16384 + (size_t)sq * 128) * 64;
    const unsigned short* kg = qkv + ((size_t)((8 + t) * 4 + b) * 16384 + (size_t)sq * 128) * 64;
    const unsigned short* vg = qkv + ((size_t)((16 + t) * 4 + b) * 8192 + (size_t)sq * 64) * 128;
    {
        int r = tid >> 3, d0 = (tid & 7) * 8;
#pragma unroll
        for (int it = 0; it < 4; ++it) {
            *(int4*)(Qs + (it * 32 + r) * 80 + d0) = *(const int4*)(qg + (it * 32 + r) * 64 + d0);
            *(int4*)(Ks + (it * 32 + r) * 80 + d0) = *(const int4*)(kg + (it * 32 + r) * 64 + d0);
        }
        int r2 = tid >> 4, i0 = (tid & 15) * 8;
#pragma unroll
        for (int it = 0; it < 4; ++it)
            *(int4*)(Vt + (it * 16 + r2) * 144 + i0) = *(const int4*)(vg + (it * 16 + r2) * 128 + i0);
    }
    __syncthreads();

    f32x4 st[8][2] = {};
#pragma unroll
    for (int kk = 0; kk < 2; ++kk) {
        int ko = kk * 32 + (lane >> 4) * 8;
        bf16x8 bq[2];
#pragma unroll
        for (int nt = 0; nt < 2; ++nt)
            bq[nt] = *(const bf16x8*)(Qs + (wv * 32 + nt * 16 + (lane & 15)) * 80 + ko);
#pragma unroll
        for (int mt = 0; mt < 8; ++mt) {
            bf16x8 ak = *(const bf16x8*)(Ks + (mt * 16 + (lane & 15)) * 80 + ko);
#pragma unroll
            for (int nt = 0; nt < 2; ++nt)
                st[mt][nt] = __builtin_amdgcn_mfma_f32_16x16x32_bf16(ak, bq[nt], st[mt][nt], 0, 0, 0);
        }
    }

    const float sc = 0.125f * 1.44269504088896f;
    float mx[2], rinv[2];
    unsigned ppk[8][2][2];
#pragma unroll
    for (int nt = 0; nt < 2; ++nt) {
        float m = -3.0e38f;
#pragma unroll
        for (int mt = 0; mt < 8; ++mt)
#pragma unroll
            for (int r = 0; r < 4; ++r)
                m = fmaxf(m, st[mt][nt][r]);
        m = fmaxf(m, __shfl_xor(m, 16));
        m = fmaxf(m, __shfl_xor(m, 32));
        mx[nt] = m * sc;
    }
#pragma unroll
    for (int nt = 0; nt < 2; ++nt) {
        float s = 0.f;
#pragma unroll
        for (int mt = 0; mt < 8; ++mt) {
            float p0 = exp2f(st[mt][nt][0] * sc - mx[nt]);
            float p1 = exp2f(st[mt][nt][1] * sc - mx[nt]);
            float p2 = exp2f(st[mt][nt][2] * sc - mx[nt]);
            float p3 = exp2f(st[mt][nt][3] * sc - mx[nt]);
            s += (p0 + p1) + (p2 + p3);
            ppk[mt][nt][0] = (unsigned)f2b(p0) | ((unsigned)f2b(p1) << 16);
            ppk[mt][nt][1] = (unsigned)f2b(p2) | ((unsigned)f2b(p3) << 16);
        }
        s += __shfl_xor(s, 16);
        s += __shfl_xor(s, 32);
        rinv[nt] = 1.0f / s;
    }

    f32x4 ov[4][2] = {};
    int g = lane >> 4;
    int ls0 = (lane & 15) | ((g & 1) << 5);
    int ls1 = ls0 | 16;
    int hi = g >> 1;
#pragma unroll
    for (int kt = 0; kt < 4; ++kt) {
        bf16x8 bp[2];
#pragma unroll
        for (int nt = 0; nt < 2; ++nt) {
            unsigned a0 = (unsigned)__shfl((int)ppk[2 * kt    ][nt][0], ls0);
            unsigned b0 = (unsigned)__shfl((int)ppk[2 * kt + 1][nt][0], ls0);
            unsigned a1 = (unsigned)__shfl((int)ppk[2 * kt    ][nt][1], ls0);
            unsigned b1 = (unsigned)__shfl((int)ppk[2 * kt + 1][nt][1], ls0);
            unsigned a2 = (unsigned)__shfl((int)ppk[2 * kt    ][nt][0], ls1);
            unsigned b2 = (unsigned)__shfl((int)ppk[2 * kt + 1][nt][0], ls1);
            unsigned a3 = (unsigned)__shfl((int)ppk[2 * kt    ][nt][1], ls1);
            unsigned b3 = (unsigned)__shfl((int)ppk[2 * kt + 1][nt][1], ls1);
            union { unsigned u[4]; bf16x8 v; } pk;
            pk.u[0] = hi ? b0 : a0;
            pk.u[1] = hi ? b1 : a1;
            pk.u[2] = hi ? b2 : a2;
            pk.u[3] = hi ? b3 : a3;
            bp[nt] = pk.v;
        }
#pragma unroll
        for (int dt = 0; dt < 4; ++dt) {
            bf16x8 av = *(const bf16x8*)(Vt + (dt * 16 + (lane & 15)) * 144 + kt * 32 + (lane >> 4) * 8);
#pragma unroll
            for (int nt = 0; nt < 2; ++nt)
                ov[dt][nt] = __builtin_amdgcn_mfma_f32_16x16x32_bf16(av, bp[nt], ov[dt][nt], 0, 0, 0);
        }
    }

#pragma unroll
    for (int dt = 0; dt < 4; ++dt) {
        int d0 = dt * 16 + (lane >> 4) * 4;
#pragma unroll
        for (int nt = 0; nt < 2; ++nt) {
            int i = wv * 32 + nt * 16 + (lane & 15);
            size_t p = ((size_t)(b * 128 + sq)) * 128 + i;
            ushort4 o;
            o.x = f2b(ov[dt][nt][0] * rinv[nt]);
            o.y = f2b(ov[dt][nt][1] * rinv[nt]);
            o.z = f2b(ov[dt][nt][2] * rinv[nt]);
            o.w = f2b(ov[dt][nt][3] * rinv[nt]);
            *(ushort4*)(o2 + p * 512 + t * 64 + d0) = o;
        }
    }
}

extern "C" void kernel_launch(void* const* d_in, const int* in_sizes, int n_in,
                              void* d_out, int out_size, void* d_ws, size_t ws_size,
                              hipStream_t stream) {
    const float* x  = (const float*)d_in[0];
    const float* wq = (const float*)d_in[1];
    const float* wp = (const float*)d_in[2];
    float* out = (float*)d_out;
    char* ws = (char*)d_ws;
    unsigned short* wqb = (unsigned short*)(ws);
    unsigned short* wpb = (unsigned short*)(ws + ((size_t)2 << 20));
    unsigned short* xb  = (unsigned short*)(ws + ((size_t)4 << 20));
    unsigned short* o2  = (unsigned short*)(ws + ((size_t)68 << 20));
    unsigned short* qkv = (unsigned short*)(ws + ((size_t)132 << 20));

    cvt_w<<<1024, 256, 0, stream>>>(wq, wp, wqb, wpb);
    k0_tr<<<8192, 256, 0, stream>>>(x, xb);
    // pass 1 (axis = h)
    gemm8<0><<<12 * 512, 256, 0, stream>>>(wqb, xb, qkv, nullptr, nullptr, 12);
    attn_k<<<4096, 256, 0, stream>>>(qkv, o2);
    gemm8<1><<<4 * 512, 256, 0, stream>>>(wpb, o2, xb, nullptr, nullptr, 4);
    // pass 2 (axis = w)
    gemm8<0><<<12 * 512, 256, 0, stream>>>(wqb, xb, qkv, nullptr, nullptr, 12);
    attn_k<<<4096, 256, 0, stream>>>(qkv, o2);
    gemm8<2><<<4 * 512, 256, 0, stream>>>(wpb, o2, nullptr, x, out, 4);
}